// Round 1
// baseline (486.221 us; speedup 1.0000x reference)
//
#include <hip/hip_runtime.h>
#include <stdint.h>

typedef unsigned long long u64;
typedef __attribute__((ext_vector_type(8))) short bf16x8;
typedef __attribute__((ext_vector_type(4))) float f32x4;

#define BATCH 512
#define FEAT 256
#define ENC 2048
#define HID 4096
#define CLS 1000
#define KTOT 12288      // 3 * 4096

#define BM 128
#define BN 128
#define BK 32
#define NSPLIT 8
#define KSPLIT (KTOT / NSPLIT)   // 1536
#define ASTRIDE 40               // bf16 elems per LDS row (32 + 8 pad)
#define PARTLD 1024              // padded N for partials

// ---------------- kernel 1: gray-encode x into bit-packed rows ----------------
// bits0: (512, 32) u64, flat bit j = feature*8 + bitpos, matching reference reshape
__global__ void k_encode(const float* __restrict__ x, u64* __restrict__ bits0) {
    int idx = blockIdx.x * blockDim.x + threadIdx.x;   // 512*32 words
    if (idx >= BATCH * 32) return;
    int b = idx >> 5, w = idx & 31;
    const float* xr = x + b * FEAT + w * 8;
    u64 word = 0;
    #pragma unroll
    for (int f = 0; f < 8; ++f) {
        float v = xr[f];
        v = fminf(fmaxf(v, 0.0f), 1.0f);
        int lev = (int)rintf(v * 255.0f);          // round-half-even == jnp.round
        unsigned gray = (unsigned)(lev ^ (lev >> 1));   // 8 bits
        word |= ((u64)gray) << (f * 8);
    }
    bits0[idx] = word;
}

// ---------------- kernel 2: extract sparse (col, sign) per W row ----------------
// one wave per row; rows 0..4095 -> W0 (K=2048), 4096..8191 -> W1, 8192..12287 -> W2
// table: 12288 rows x 32 u16 entries (col | sign<<15); counts: per-row nnz
__global__ void k_sparsify(const float* __restrict__ W0, const float* __restrict__ W1,
                           const float* __restrict__ W2,
                           uint16_t* __restrict__ table, int* __restrict__ counts) {
    int wid = blockIdx.x * 4 + (threadIdx.x >> 6);
    int lane = threadIdx.x & 63;
    int row = wid;
    const float* W; int K; int local;
    if (row < HID)          { W = W0; K = ENC; local = row; }
    else if (row < 2 * HID) { W = W1; K = HID; local = row - HID; }
    else                    { W = W2; K = HID; local = row - 2 * HID; }
    const float* r = W + (size_t)local * K;
    uint16_t* te = table + (size_t)row * 32;
    int cnt = 0;
    for (int base = 0; base < K; base += 64) {
        float v = r[base + lane];
        u64 mask = __ballot(v != 0.0f);
        if (v != 0.0f) {
            int pre = __popcll(mask & ((1ull << lane) - 1ull));
            te[cnt + pre] = (uint16_t)((unsigned)(base + lane) | ((v < 0.0f) ? 0x8000u : 0u));
        }
        cnt += __popcll(mask);
    }
    if (lane == 0) counts[row] = cnt;
}

// ---------------- kernel 3: one sparse layer, exact integer z, pack activation bits ----
// wave = (batch b, neuron-group ng); lane = neuron within group; ballot packs 64 bits
__global__ void k_layer(const u64* __restrict__ prev, int prevWords,
                        const uint16_t* __restrict__ table, const int* __restrict__ counts,
                        u64* __restrict__ actOut) {
    int wid = blockIdx.x * 4 + (threadIdx.x >> 6);
    int lane = threadIdx.x & 63;
    int b  = wid >> 6;                 // 0..511
    int ng = wid & 63;                 // 0..63
    int n  = ng * 64 + lane;           // 0..4095
    const u64* rowbits = prev + (size_t)b * prevWords;
    const uint16_t* te = table + (size_t)n * 32;
    int cnt = counts[n];
    int z = 0;
    const uint4* tq = (const uint4*)te;     // 64B, 16-aligned
    #pragma unroll
    for (int q = 0; q < 4; ++q) {
        uint4 e4 = tq[q];
        unsigned es[4] = {e4.x, e4.y, e4.z, e4.w};
        #pragma unroll
        for (int h = 0; h < 4; ++h) {
            #pragma unroll
            for (int s = 0; s < 2; ++s) {
                int e = q * 8 + h * 2 + s;
                unsigned ent = (es[h] >> (s * 16)) & 0xFFFFu;
                if (e < cnt) {
                    int col = (int)(ent & 0x7FFFu);
                    u64 wv = rowbits[col >> 6];
                    int bit = (int)((wv >> (col & 63)) & 1ull);
                    z += (ent & 0x8000u) ? -bit : bit;
                }
            }
        }
    }
    u64 res = __ballot(z >= 4);       // z integer; z >= 4.0 exact
    if (lane == 0) actOut[(size_t)b * 64 + ng] = res;
}

// ---------------- kernel 4: out-projection GEMM, bf16 MFMA, split-K partials ----------
static __device__ inline short f2bf(float f) {
    unsigned u = __float_as_uint(f);
    unsigned r = (u + 0x7FFFu + ((u >> 16) & 1u)) >> 16;   // RNE
    return (short)r;
}

__global__ void __launch_bounds__(256)
k_outgemm(const u64* __restrict__ act,       // (3, 512, 64) u64 activation bits
          const float* __restrict__ out_w,   // (12288, 1000) fp32
          float* __restrict__ part) {        // (NSPLIT, 512, 1024) fp32 partials
    __shared__ __attribute__((aligned(16))) short As[BM * ASTRIDE];
    __shared__ __attribute__((aligned(16))) short Bs[BN * ASTRIDE];
    int bid = blockIdx.x;
    int mt = bid & 3;            // 4 M-tiles of 128 (=512)
    int nt = (bid >> 2) & 7;     // 8 N-tiles of 128 (pad 1000->1024)
    int ks = bid >> 5;           // split-K index
    int tid = threadIdx.x;
    int lane = tid & 63;
    int wv = tid >> 6;
    int waveM = wv & 1, waveN = wv >> 1;
    int quad = lane >> 4;
    int cl = lane & 15;

    f32x4 acc[4][4] = {};
    int k0 = ks * KSPLIT;
    for (int kk = 0; kk < KSPLIT; kk += BK) {
        int kg = k0 + kk;           // 32-aligned
        int l  = kg >> 12;          // layer (4096-aligned regions)
        int nk = kg & 4095;
        int wrd = nk >> 6;
        int sh  = nk & 63;          // 0 or 32
        // ---- stage A: 128 rows x 32 bits -> bf16, 2 threads/row ----
        {
            int rrow = tid >> 1;
            int half = tid & 1;
            int brow = mt * BM + rrow;
            u64 wval = act[((size_t)l * BATCH + brow) * 64 + wrd];
            unsigned bits = (unsigned)((wval >> sh) & 0xFFFFFFFFull);
            unsigned hb = bits >> (half * 16);
            short* dst = &As[rrow * ASTRIDE + half * 16];
            #pragma unroll
            for (int j = 0; j < 8; ++j) {
                unsigned two = hb >> (j * 2);
                unsigned pack = ((two & 1u) ? 0x3F80u : 0u) | ((two & 2u) ? 0x3F800000u : 0u);
                *(unsigned*)(dst + j * 2) = pack;
            }
        }
        // ---- stage B: 32 k-rows x 128 cols fp32 -> bf16, transposed to Bs[c][k] ----
        #pragma unroll
        for (int i = 0; i < 4; ++i) {
            int idx = tid + i * 256;      // 0..1023
            int kr = idx >> 5;            // 0..31
            int c4 = idx & 31;            // col group of 4
            int c  = nt * BN + c4 * 4;
            float4 bv;
            if (c < CLS) {                 // 1000 % 4 == 0: full or fully OOB
                bv = *(const float4*)(&out_w[(size_t)(kg + kr) * CLS + c]);
            } else {
                bv.x = bv.y = bv.z = bv.w = 0.0f;
            }
            short* bd = &Bs[(c4 * 4) * ASTRIDE + kr];
            bd[0 * ASTRIDE] = f2bf(bv.x);
            bd[1 * ASTRIDE] = f2bf(bv.y);
            bd[2 * ASTRIDE] = f2bf(bv.z);
            bd[3 * ASTRIDE] = f2bf(bv.w);
        }
        __syncthreads();
        // ---- compute: wave 64x64 = 4x4 MFMA 16x16x32 frags ----
        bf16x8 af[4], bfr[4];
        #pragma unroll
        for (int mf = 0; mf < 4; ++mf) {
            int m = waveM * 64 + mf * 16 + cl;
            af[mf] = *(const bf16x8*)(&As[m * ASTRIDE + quad * 8]);
        }
        #pragma unroll
        for (int nf = 0; nf < 4; ++nf) {
            int n = waveN * 64 + nf * 16 + cl;
            bfr[nf] = *(const bf16x8*)(&Bs[n * ASTRIDE + quad * 8]);
        }
        #pragma unroll
        for (int mf = 0; mf < 4; ++mf)
            #pragma unroll
            for (int nf = 0; nf < 4; ++nf)
                acc[mf][nf] = __builtin_amdgcn_mfma_f32_16x16x32_bf16(
                    af[mf], bfr[nf], acc[mf][nf], 0, 0, 0);
        __syncthreads();
    }
    // ---- epilogue: store fp32 partials (C/D map: col=lane&15, row=quad*4+reg) ----
    float* pbase = part + (size_t)ks * (BATCH * PARTLD);
    #pragma unroll
    for (int mf = 0; mf < 4; ++mf) {
        #pragma unroll
        for (int nf = 0; nf < 4; ++nf) {
            int cp = nt * BN + waveN * 64 + nf * 16 + cl;       // 0..1023
            #pragma unroll
            for (int r = 0; r < 4; ++r) {
                int mg = mt * BM + waveM * 64 + mf * 16 + quad * 4 + r;
                pbase[(size_t)mg * PARTLD + cp] = acc[mf][nf][r];
            }
        }
    }
}

// ---------------- kernel 5: reduce split-K partials into out ----------------
__global__ void k_reduce(const float* __restrict__ part, float* __restrict__ out) {
    int idx = blockIdx.x * blockDim.x + threadIdx.x;
    if (idx >= BATCH * CLS) return;
    int b = idx / CLS, c = idx % CLS;
    float s = 0.0f;
    #pragma unroll
    for (int sp = 0; sp < NSPLIT; ++sp)
        s += part[((size_t)sp * BATCH + b) * PARTLD + c];
    out[idx] = s;
}

extern "C" void kernel_launch(void* const* d_in, const int* in_sizes, int n_in,
                              void* d_out, int out_size, void* d_ws, size_t ws_size,
                              hipStream_t stream) {
    const float* x     = (const float*)d_in[0];
    const float* W0    = (const float*)d_in[1];
    const float* W1    = (const float*)d_in[2];
    const float* W2    = (const float*)d_in[3];
    const float* out_w = (const float*)d_in[4];
    float* out = (float*)d_out;
    char* ws = (char*)d_ws;

    // ws layout (bytes)
    u64*      bits0  = (u64*)(ws + 0);              // 512*32*8   = 131072
    u64*      act    = (u64*)(ws + 131072);         // 3*512*64*8 = 786432
    uint16_t* table  = (uint16_t*)(ws + 917504);    // 12288*32*2 = 786432
    int*      counts = (int*)(ws + 1703936);        // 12288*4    = 49152
    float*    part   = (float*)(ws + 1753088);      // 8*512*1024*4 = 16777216

    hipLaunchKernelGGL(k_encode, dim3((BATCH * 32 + 255) / 256), dim3(256), 0, stream,
                       x, bits0);
    hipLaunchKernelGGL(k_sparsify, dim3(3 * HID / 4), dim3(256), 0, stream,
                       W0, W1, W2, table, counts);
    hipLaunchKernelGGL(k_layer, dim3(BATCH * 64 / 4), dim3(256), 0, stream,
                       bits0, 32, table, counts, act);
    hipLaunchKernelGGL(k_layer, dim3(BATCH * 64 / 4), dim3(256), 0, stream,
                       act, 64, table + (size_t)HID * 32, counts + HID, act + BATCH * 64);
    hipLaunchKernelGGL(k_layer, dim3(BATCH * 64 / 4), dim3(256), 0, stream,
                       act + BATCH * 64, 64, table + (size_t)2 * HID * 32, counts + 2 * HID,
                       act + 2 * BATCH * 64);
    hipLaunchKernelGGL(k_outgemm, dim3(4 * 8 * NSPLIT), dim3(256), 0, stream,
                       act, out_w, part);
    hipLaunchKernelGGL(k_reduce, dim3((BATCH * CLS + 255) / 256), dim3(256), 0, stream,
                       part, out);
}

// Round 2
// 352.261 us; speedup vs baseline: 1.3803x; 1.3803x over previous
//
#include <hip/hip_runtime.h>
#include <stdint.h>

typedef unsigned long long u64;
typedef __attribute__((ext_vector_type(8))) short bf16x8;
typedef __attribute__((ext_vector_type(4))) float f32x4;

#define BATCH 512
#define FEAT 256
#define ENC 2048
#define HID 4096
#define CLS 1000
#define KTOT 12288      // 3 * 4096
#define NSPLIT 16
#define KSPLIT (KTOT / NSPLIT)   // 768

// ---------- fp32 -> bf16 RNE ----------
static __device__ inline unsigned short f2bf(float f) {
    unsigned u = __float_as_uint(f);
    return (unsigned short)((u + 0x7FFFu + ((u >> 16) & 1u)) >> 16);
}

// ---------- async global->LDS, 16B/lane ----------
static __device__ inline void gld16(const void* g, void* s) {
    __builtin_amdgcn_global_load_lds((const __attribute__((address_space(1))) void*)g,
                                     (__attribute__((address_space(3))) void*)s, 16, 0, 0);
}

// ================= kernel 1: encode, bits packed OVER BATCH =================
// enc2[bg][k] u64: bit b' = batch (bg*64+b')'s gray bit for feature-bit k = f*8+bit
__global__ void k_encode(const float* __restrict__ x, u64* __restrict__ enc2) {
    int wid = blockIdx.x * 4 + (threadIdx.x >> 6);   // 2048 waves
    int lane = threadIdx.x & 63;
    int f = wid >> 3, bg = wid & 7;
    float v = x[(size_t)(bg * 64 + lane) * FEAT + f];
    v = fminf(fmaxf(v, 0.0f), 1.0f);
    int lev = (int)rintf(v * 255.0f);                // round-half-even == jnp.round
    unsigned gray = (unsigned)(lev ^ (lev >> 1));
    u64 w = 0;
    #pragma unroll
    for (int bit = 0; bit < 8; ++bit) {
        u64 m = __ballot((gray >> bit) & 1u);
        if (lane == bit) w = m;
    }
    if (lane < 8) enc2[(size_t)bg * ENC + f * 8 + lane] = w;
}

// ================= kernel 2: sparse table extraction (float4 scan) =================
__global__ void k_sparsify(const float* __restrict__ W0, const float* __restrict__ W1,
                           const float* __restrict__ W2,
                           uint16_t* __restrict__ table, int* __restrict__ counts) {
    int row = blockIdx.x * 4 + (threadIdx.x >> 6);
    int lane = threadIdx.x & 63;
    const float* W; int K; int local;
    if (row < HID)          { W = W0; K = ENC; local = row; }
    else if (row < 2 * HID) { W = W1; K = HID; local = row - HID; }
    else                    { W = W2; K = HID; local = row - 2 * HID; }
    const float4* r4 = (const float4*)(W + (size_t)local * K);
    uint16_t* te = table + (size_t)row * 32;
    u64 low = (1ull << lane) - 1ull;
    int cnt = 0;
    for (int base = 0; base < K; base += 256) {
        float4 v = r4[(base >> 2) + lane];
        u64 m0 = __ballot(v.x != 0.0f);
        u64 m1 = __ballot(v.y != 0.0f);
        u64 m2 = __ballot(v.z != 0.0f);
        u64 m3 = __ballot(v.w != 0.0f);
        int pre = __popcll(m0 & low) + __popcll(m1 & low) + __popcll(m2 & low) + __popcll(m3 & low);
        int b0 = (int)((m0 >> lane) & 1), b1 = (int)((m1 >> lane) & 1);
        int b2 = (int)((m2 >> lane) & 1), b3 = (int)((m3 >> lane) & 1);
        int c0 = base + lane * 4;
        if (b0) te[cnt + pre]                = (uint16_t)((unsigned)c0       | ((v.x < 0.0f) ? 0x8000u : 0u));
        if (b1) te[cnt + pre + b0]           = (uint16_t)((unsigned)(c0 + 1) | ((v.y < 0.0f) ? 0x8000u : 0u));
        if (b2) te[cnt + pre + b0 + b1]      = (uint16_t)((unsigned)(c0 + 2) | ((v.z < 0.0f) ? 0x8000u : 0u));
        if (b3) te[cnt + pre + b0 + b1 + b2] = (uint16_t)((unsigned)(c0 + 3) | ((v.w < 0.0f) ? 0x8000u : 0u));
        cnt += __popcll(m0) + __popcll(m1) + __popcll(m2) + __popcll(m3);
    }
    if (lane == 0) counts[row] = cnt;
}

// ================= kernel 3: layer, lanes = batch, scalar synapse loads =================
// prev2[bg][col] u64 (bits over batch). Output act2[bg][n] u64 via ballot.
__global__ void k_layer(const u64* __restrict__ prev2, int Kstride,
                        const uint16_t* __restrict__ table, const int* __restrict__ counts,
                        u64* __restrict__ actout) {
    int wid = __builtin_amdgcn_readfirstlane(blockIdx.x * 4 + (threadIdx.x >> 6));
    int lane = threadIdx.x & 63;
    int n = wid >> 3, bg = wid & 7;
    const u64* prow = prev2 + (size_t)bg * Kstride;
    const uint4* tq = (const uint4*)(table + (size_t)n * 32);
    int cnt = counts[n];
    int z = 0;
    #pragma unroll
    for (int q = 0; q < 4; ++q) {
        uint4 e4 = tq[q];
        unsigned es[4] = {e4.x, e4.y, e4.z, e4.w};
        #pragma unroll
        for (int h = 0; h < 4; ++h) {
            #pragma unroll
            for (int s2 = 0; s2 < 2; ++s2) {
                int e = q * 8 + h * 2 + s2;
                if (e < cnt) {
                    unsigned ent = (es[h] >> (s2 * 16)) & 0xFFFFu;
                    u64 w = prow[ent & 0x7FFFu];             // wave-uniform -> scalar load
                    int bit = (int)((w >> lane) & 1ull);
                    z += (ent & 0x8000u) ? -bit : bit;
                }
            }
        }
    }
    u64 res = __ballot(z >= 4);
    if (lane == 0) actout[(size_t)bg * HID + n] = res;
}

// ================= kernel 4: expand activation bits -> bf16 Ag (swizzled) =================
// Ag[b][kk], kk-chunk of 64 stores group g at position (g ^ (b&7))
__global__ void k_expandA(const u64* __restrict__ act2, short* __restrict__ Ag) {
    int idx = blockIdx.x * 256 + threadIdx.x;     // 512*3*512 = 786432
    int b = idx / 1536;
    int rem = idx - b * 1536;
    int l = rem >> 9;
    int chunk = rem & 511;                        // n-chunk of 8
    int bg = b >> 6, bl = b & 63;
    const u64* src = act2 + ((size_t)l * 8 + bg) * HID + chunk * 8;
    unsigned sh[8];
    #pragma unroll
    for (int j = 0; j < 8; ++j) sh[j] = ((src[j] >> bl) & 1ull) ? 0x3F80u : 0u;
    int g = chunk & 7, c64 = chunk >> 3;
    short* dst = Ag + (size_t)b * KTOT + l * HID + c64 * 64 + ((g ^ (b & 7)) * 8);
    uint4 pk;
    pk.x = sh[0] | (sh[1] << 16);
    pk.y = sh[2] | (sh[3] << 16);
    pk.z = sh[4] | (sh[5] << 16);
    pk.w = sh[6] | (sh[7] << 16);
    *(uint4*)dst = pk;
}

// ================= kernel 5: transpose+convert out_w -> wt bf16 (swizzled) =================
// wt[c][k], c padded to 1024 (zeros), per-64-k-chunk group g stored at (g ^ (c&7))
__global__ void k_twt(const float* __restrict__ out_w, short* __restrict__ wt) {
    __shared__ short tile[64 * 68];
    int kt = blockIdx.x % 192, ct = blockIdx.x / 192;
    int k0 = kt * 64, c0 = ct * 64;
    int t = threadIdx.x;
    {
        int rrow = t >> 4, c4 = t & 15;
        int c = c0 + c4 * 4;
        #pragma unroll
        for (int rd = 0; rd < 4; ++rd) {
            int kl = rd * 16 + rrow;
            float4 v;
            if (c < CLS) v = *(const float4*)&out_w[(size_t)(k0 + kl) * CLS + c];
            else { v.x = v.y = v.z = v.w = 0.0f; }
            short* d = &tile[kl * 68 + c4 * 4];
            d[0] = (short)f2bf(v.x); d[1] = (short)f2bf(v.y);
            d[2] = (short)f2bf(v.z); d[3] = (short)f2bf(v.w);
        }
    }
    __syncthreads();
    {
        int chunk = t & 7, cl2 = t >> 3;
        #pragma unroll
        for (int rd = 0; rd < 2; ++rd) {
            int c_local = rd * 32 + cl2;
            int c = c0 + c_local;
            unsigned s8[8];
            #pragma unroll
            for (int j = 0; j < 8; ++j)
                s8[j] = (unsigned)(unsigned short)tile[(chunk * 8 + j) * 68 + c_local];
            uint4 pk;
            pk.x = s8[0] | (s8[1] << 16);
            pk.y = s8[2] | (s8[3] << 16);
            pk.z = s8[4] | (s8[5] << 16);
            pk.w = s8[6] | (s8[7] << 16);
            *(uint4*)&wt[(size_t)c * KTOT + k0 + ((chunk ^ (c & 7)) * 8)] = pk;
        }
    }
}

// ================= kernel 6: GEMM, m97 structure, global_load_lds, split-K atomics ======
__global__ void __launch_bounds__(256)
k_gemm(const short* __restrict__ Ag, const short* __restrict__ wt, float* __restrict__ out) {
    __shared__ __attribute__((aligned(16))) short As[128 * 64];
    __shared__ __attribute__((aligned(16))) short Bs[128 * 64];
    int bid = blockIdx.x;
    int mt = bid & 3, nt = (bid >> 2) & 7, ks = bid >> 5;
    int tid = threadIdx.x, lane = tid & 63;
    int wv = tid >> 6, waveM = wv & 1, waveN = wv >> 1;
    int quad = lane >> 4, cl = lane & 15;
    f32x4 acc[4][4] = {};
    const char* Ab = (const char*)(Ag + (size_t)mt * 128 * KTOT + ks * KSPLIT);
    const char* Bb = (const char*)(wt + (size_t)nt * 128 * KTOT + ks * KSPLIT);
    int r = tid >> 3, sub = tid & 7;
    for (int kk = 0; kk < KSPLIT; kk += 64) {
        #pragma unroll
        for (int rd = 0; rd < 4; ++rd) {
            size_t go = (size_t)(r + rd * 32) * (KTOT * 2) + kk * 2 + sub * 16;
            gld16(Ab + go, &As[(tid + rd * 256) * 8]);
            gld16(Bb + go, &Bs[(tid + rd * 256) * 8]);
        }
        __syncthreads();
        #pragma unroll
        for (int s = 0; s < 2; ++s) {
            int xr = ((s * 4 + quad) ^ (cl & 7)) * 8;
            bf16x8 af[4], bfr[4];
            #pragma unroll
            for (int mf = 0; mf < 4; ++mf)
                af[mf] = *(const bf16x8*)&As[(waveM * 64 + mf * 16 + cl) * 64 + xr];
            #pragma unroll
            for (int nf = 0; nf < 4; ++nf)
                bfr[nf] = *(const bf16x8*)&Bs[(waveN * 64 + nf * 16 + cl) * 64 + xr];
            #pragma unroll
            for (int mf = 0; mf < 4; ++mf)
                #pragma unroll
                for (int nf = 0; nf < 4; ++nf)
                    acc[mf][nf] = __builtin_amdgcn_mfma_f32_16x16x32_bf16(
                        af[mf], bfr[nf], acc[mf][nf], 0, 0, 0);
        }
        __syncthreads();
    }
    #pragma unroll
    for (int mf = 0; mf < 4; ++mf) {
        #pragma unroll
        for (int nf = 0; nf < 4; ++nf) {
            int cp = nt * 128 + waveN * 64 + nf * 16 + cl;
            if (cp < CLS) {
                #pragma unroll
                for (int rr = 0; rr < 4; ++rr) {
                    int mg = mt * 128 + waveM * 64 + mf * 16 + quad * 4 + rr;
                    atomicAdd(&out[(size_t)mg * CLS + cp], acc[mf][nf][rr]);
                }
            }
        }
    }
}

extern "C" void kernel_launch(void* const* d_in, const int* in_sizes, int n_in,
                              void* d_out, int out_size, void* d_ws, size_t ws_size,
                              hipStream_t stream) {
    const float* x     = (const float*)d_in[0];
    const float* W0    = (const float*)d_in[1];
    const float* W1    = (const float*)d_in[2];
    const float* W2    = (const float*)d_in[3];
    const float* out_w = (const float*)d_in[4];
    float* out = (float*)d_out;
    char* ws = (char*)d_ws;

    // ws layout (bytes), total ~39.5 MB
    u64*      enc2   = (u64*)(ws + 0);              // 8*2048*8      = 131072
    u64*      act2   = (u64*)(ws + 131072);         // 3*8*4096*8    = 786432
    uint16_t* table  = (uint16_t*)(ws + 917504);    // 12288*32*2    = 786432
    int*      counts = (int*)(ws + 1703936);        // 12288*4       = 49152
    short*    Ag     = (short*)(ws + 1753088);      // 512*12288*2   = 12582912
    short*    wt     = (short*)(ws + 14336000);     // 1024*12288*2  = 25165824

    hipMemsetAsync(d_out, 0, (size_t)BATCH * CLS * sizeof(float), stream);
    hipLaunchKernelGGL(k_encode, dim3(512), dim3(256), 0, stream, x, enc2);
    hipLaunchKernelGGL(k_sparsify, dim3(3 * HID / 4), dim3(256), 0, stream,
                       W0, W1, W2, table, counts);
    hipLaunchKernelGGL(k_twt, dim3(3072), dim3(256), 0, stream, out_w, wt);
    hipLaunchKernelGGL(k_layer, dim3(HID * 8 / 4), dim3(256), 0, stream,
                       enc2, ENC, table, counts, act2);
    hipLaunchKernelGGL(k_layer, dim3(HID * 8 / 4), dim3(256), 0, stream,
                       act2, HID, table + (size_t)HID * 32, counts + HID, act2 + 8 * HID);
    hipLaunchKernelGGL(k_layer, dim3(HID * 8 / 4), dim3(256), 0, stream,
                       act2 + 8 * HID, HID, table + (size_t)2 * HID * 32, counts + 2 * HID,
                       act2 + 16 * HID);
    hipLaunchKernelGGL(k_expandA, dim3(3072), dim3(256), 0, stream, act2, Ag);
    hipLaunchKernelGGL(k_gemm, dim3(4 * 8 * NSPLIT), dim3(256), 0, stream, Ag, wt, out);
}

// Round 3
// 350.106 us; speedup vs baseline: 1.3888x; 1.0062x over previous
//
#include <hip/hip_runtime.h>
#include <stdint.h>

typedef unsigned long long u64;
typedef __attribute__((ext_vector_type(8))) short bf16x8;
typedef __attribute__((ext_vector_type(4))) float f32x4;

#define BATCH 512
#define FEAT 256
#define ENC 2048
#define HID 4096
#define CLS 1000
#define KTOT 12288      // 3 * 4096
#define NSPLIT 16
#define KSPLIT (KTOT / NSPLIT)   // 768

// ---------- fp32 -> bf16 RNE ----------
static __device__ inline unsigned short f2bf(float f) {
    unsigned u = __float_as_uint(f);
    return (unsigned short)((u + 0x7FFFu + ((u >> 16) & 1u)) >> 16);
}

// ---------- async global->LDS, 16B/lane ----------
static __device__ inline void gld16(const void* g, void* s) {
    __builtin_amdgcn_global_load_lds((const __attribute__((address_space(1))) void*)g,
                                     (__attribute__((address_space(3))) void*)s, 16, 0, 0);
}

// ================= kernel 1: fused prep = encode | sparsify | twt =================
// blocks [0,512): encode   [512,3584): sparsify   [3584,6656): twt
__global__ void __launch_bounds__(256)
k_prep(const float* __restrict__ x, u64* __restrict__ enc2,
       const float* __restrict__ W0, const float* __restrict__ W1,
       const float* __restrict__ W2,
       uint16_t* __restrict__ table, int* __restrict__ counts,
       const float* __restrict__ out_w, short* __restrict__ wt) {
    __shared__ short tile[64 * 68];
    int bid = blockIdx.x;
    int t = threadIdx.x;
    int lane = t & 63;

    if (bid < 512) {
        // ---- encode: bits packed OVER BATCH ----
        int wid = bid * 4 + (t >> 6);
        int f = wid >> 3, bg = wid & 7;
        float v = x[(size_t)(bg * 64 + lane) * FEAT + f];
        v = fminf(fmaxf(v, 0.0f), 1.0f);
        int lev = (int)rintf(v * 255.0f);                // RNE == jnp.round
        unsigned gray = (unsigned)(lev ^ (lev >> 1));
        u64 w = 0;
        #pragma unroll
        for (int bit = 0; bit < 8; ++bit) {
            u64 m = __ballot((gray >> bit) & 1u);
            if (lane == bit) w = m;
        }
        if (lane < 8) enc2[(size_t)bg * ENC + f * 8 + lane] = w;
        return;
    }
    if (bid < 3584) {
        // ---- sparsify: 8 independent float4 loads hoisted ahead of processing ----
        int row = (bid - 512) * 4 + (t >> 6);
        const float* W; int K; int local;
        if (row < HID)          { W = W0; K = ENC; local = row; }
        else if (row < 2 * HID) { W = W1; K = HID; local = row - HID; }
        else                    { W = W2; K = HID; local = row - 2 * HID; }
        const float4* r4 = (const float4*)(W + (size_t)local * K);
        uint16_t* te = table + (size_t)row * 32;
        u64 low = (1ull << lane) - 1ull;
        int cnt = 0;
        for (int base = 0; base < K; base += 2048) {
            float4 v[8];
            #pragma unroll
            for (int j = 0; j < 8; ++j)
                v[j] = r4[((base + j * 256) >> 2) + lane];
            #pragma unroll
            for (int j = 0; j < 8; ++j) {
                u64 m0 = __ballot(v[j].x != 0.0f);
                u64 m1 = __ballot(v[j].y != 0.0f);
                u64 m2 = __ballot(v[j].z != 0.0f);
                u64 m3 = __ballot(v[j].w != 0.0f);
                int pre = __popcll(m0 & low) + __popcll(m1 & low)
                        + __popcll(m2 & low) + __popcll(m3 & low);
                int b0 = (int)((m0 >> lane) & 1), b1 = (int)((m1 >> lane) & 1);
                int b2 = (int)((m2 >> lane) & 1), b3 = (int)((m3 >> lane) & 1);
                int c0 = base + j * 256 + lane * 4;
                if (b0) te[cnt + pre]                = (uint16_t)((unsigned)c0       | ((v[j].x < 0.0f) ? 0x8000u : 0u));
                if (b1) te[cnt + pre + b0]           = (uint16_t)((unsigned)(c0 + 1) | ((v[j].y < 0.0f) ? 0x8000u : 0u));
                if (b2) te[cnt + pre + b0 + b1]      = (uint16_t)((unsigned)(c0 + 2) | ((v[j].z < 0.0f) ? 0x8000u : 0u));
                if (b3) te[cnt + pre + b0 + b1 + b2] = (uint16_t)((unsigned)(c0 + 3) | ((v[j].w < 0.0f) ? 0x8000u : 0u));
                cnt += __popcll(m0) + __popcll(m1) + __popcll(m2) + __popcll(m3);
            }
        }
        if (lane == 0) counts[row] = cnt;
        return;
    }
    {
        // ---- twt: transpose+convert out_w -> wt bf16 (swizzled) ----
        int b2 = bid - 3584;
        int kt = b2 % 192, ct = b2 / 192;
        int k0 = kt * 64, c0 = ct * 64;
        {
            int rrow = t >> 4, c4 = t & 15;
            int c = c0 + c4 * 4;
            #pragma unroll
            for (int rd = 0; rd < 4; ++rd) {
                int kl = rd * 16 + rrow;
                float4 v;
                if (c < CLS) v = *(const float4*)&out_w[(size_t)(k0 + kl) * CLS + c];
                else { v.x = v.y = v.z = v.w = 0.0f; }
                short* d = &tile[kl * 68 + c4 * 4];
                d[0] = (short)f2bf(v.x); d[1] = (short)f2bf(v.y);
                d[2] = (short)f2bf(v.z); d[3] = (short)f2bf(v.w);
            }
        }
        __syncthreads();
        {
            int chunk = t & 7, cl2 = t >> 3;
            #pragma unroll
            for (int rd = 0; rd < 2; ++rd) {
                int c_local = rd * 32 + cl2;
                int c = c0 + c_local;
                unsigned s8[8];
                #pragma unroll
                for (int j = 0; j < 8; ++j)
                    s8[j] = (unsigned)(unsigned short)tile[(chunk * 8 + j) * 68 + c_local];
                uint4 pk;
                pk.x = s8[0] | (s8[1] << 16);
                pk.y = s8[2] | (s8[3] << 16);
                pk.z = s8[4] | (s8[5] << 16);
                pk.w = s8[6] | (s8[7] << 16);
                *(uint4*)&wt[(size_t)c * KTOT + k0 + ((chunk ^ (c & 7)) * 8)] = pk;
            }
        }
    }
}

// ================= kernel 2: layer, lanes = batch, wave-uniform synapse loads =========
__global__ void k_layer(const u64* __restrict__ prev2, int Kstride,
                        const uint16_t* __restrict__ table, const int* __restrict__ counts,
                        u64* __restrict__ actout) {
    int wid = __builtin_amdgcn_readfirstlane(blockIdx.x * 4 + (threadIdx.x >> 6));
    int lane = threadIdx.x & 63;
    int n = wid >> 3, bg = wid & 7;
    const u64* prow = prev2 + (size_t)bg * Kstride;
    const uint4* tq = (const uint4*)(table + (size_t)n * 32);
    int cnt = counts[n];
    int z = 0;
    #pragma unroll
    for (int q = 0; q < 4; ++q) {
        uint4 e4 = tq[q];
        unsigned es[4] = {e4.x, e4.y, e4.z, e4.w};
        #pragma unroll
        for (int h = 0; h < 4; ++h) {
            #pragma unroll
            for (int s2 = 0; s2 < 2; ++s2) {
                int e = q * 8 + h * 2 + s2;
                if (e < cnt) {
                    unsigned ent = (es[h] >> (s2 * 16)) & 0xFFFFu;
                    u64 w = prow[ent & 0x7FFFu];
                    int bit = (int)((w >> lane) & 1ull);
                    z += (ent & 0x8000u) ? -bit : bit;
                }
            }
        }
    }
    u64 res = __ballot(z >= 4);
    if (lane == 0) actout[(size_t)bg * HID + n] = res;
}

// ================= kernel 3: expand activation bits -> bf16 Ag (swizzled) =============
__global__ void k_expandA(const u64* __restrict__ act2, short* __restrict__ Ag) {
    int idx = blockIdx.x * 256 + threadIdx.x;     // 786432
    int b = idx / 1536;
    int rem = idx - b * 1536;
    int l = rem >> 9;
    int chunk = rem & 511;
    int bg = b >> 6, bl = b & 63;
    const u64* src = act2 + ((size_t)l * 8 + bg) * HID + chunk * 8;
    unsigned sh[8];
    #pragma unroll
    for (int j = 0; j < 8; ++j) sh[j] = ((src[j] >> bl) & 1ull) ? 0x3F80u : 0u;
    int g = chunk & 7, c64 = chunk >> 3;
    short* dst = Ag + (size_t)b * KTOT + l * HID + c64 * 64 + ((g ^ (b & 7)) * 8);
    uint4 pk;
    pk.x = sh[0] | (sh[1] << 16);
    pk.y = sh[2] | (sh[3] << 16);
    pk.z = sh[4] | (sh[5] << 16);
    pk.w = sh[6] | (sh[7] << 16);
    *(uint4*)dst = pk;
}

// ================= kernel 4: GEMM, m97 structure, global_load_lds, split-K atomics =====
__global__ void __launch_bounds__(256)
k_gemm(const short* __restrict__ Ag, const short* __restrict__ wt, float* __restrict__ out) {
    __shared__ __attribute__((aligned(16))) short As[128 * 64];
    __shared__ __attribute__((aligned(16))) short Bs[128 * 64];
    int bid = blockIdx.x;
    int mt = bid & 3, nt = (bid >> 2) & 7, ks = bid >> 5;
    int tid = threadIdx.x, lane = tid & 63;
    int wv = tid >> 6, waveM = wv & 1, waveN = wv >> 1;
    int quad = lane >> 4, cl = lane & 15;
    f32x4 acc[4][4] = {};
    const char* Ab = (const char*)(Ag + (size_t)mt * 128 * KTOT + ks * KSPLIT);
    const char* Bb = (const char*)(wt + (size_t)nt * 128 * KTOT + ks * KSPLIT);
    int r = tid >> 3, sub = tid & 7;
    for (int kk = 0; kk < KSPLIT; kk += 64) {
        #pragma unroll
        for (int rd = 0; rd < 4; ++rd) {
            size_t go = (size_t)(r + rd * 32) * (KTOT * 2) + kk * 2 + sub * 16;
            gld16(Ab + go, &As[(tid + rd * 256) * 8]);
            gld16(Bb + go, &Bs[(tid + rd * 256) * 8]);
        }
        __syncthreads();
        #pragma unroll
        for (int s = 0; s < 2; ++s) {
            int xr = ((s * 4 + quad) ^ (cl & 7)) * 8;
            bf16x8 af[4], bfr[4];
            #pragma unroll
            for (int mf = 0; mf < 4; ++mf)
                af[mf] = *(const bf16x8*)&As[(waveM * 64 + mf * 16 + cl) * 64 + xr];
            #pragma unroll
            for (int nf = 0; nf < 4; ++nf)
                bfr[nf] = *(const bf16x8*)&Bs[(waveN * 64 + nf * 16 + cl) * 64 + xr];
            #pragma unroll
            for (int mf = 0; mf < 4; ++mf)
                #pragma unroll
                for (int nf = 0; nf < 4; ++nf)
                    acc[mf][nf] = __builtin_amdgcn_mfma_f32_16x16x32_bf16(
                        af[mf], bfr[nf], acc[mf][nf], 0, 0, 0);
        }
        __syncthreads();
    }
    #pragma unroll
    for (int mf = 0; mf < 4; ++mf) {
        #pragma unroll
        for (int nf = 0; nf < 4; ++nf) {
            int cp = nt * 128 + waveN * 64 + nf * 16 + cl;
            if (cp < CLS) {
                #pragma unroll
                for (int rr = 0; rr < 4; ++rr) {
                    int mg = mt * 128 + waveM * 64 + mf * 16 + quad * 4 + rr;
                    atomicAdd(&out[(size_t)mg * CLS + cp], acc[mf][nf][rr]);
                }
            }
        }
    }
}

extern "C" void kernel_launch(void* const* d_in, const int* in_sizes, int n_in,
                              void* d_out, int out_size, void* d_ws, size_t ws_size,
                              hipStream_t stream) {
    const float* x     = (const float*)d_in[0];
    const float* W0    = (const float*)d_in[1];
    const float* W1    = (const float*)d_in[2];
    const float* W2    = (const float*)d_in[3];
    const float* out_w = (const float*)d_in[4];
    float* out = (float*)d_out;
    char* ws = (char*)d_ws;

    u64*      enc2   = (u64*)(ws + 0);              // 8*2048*8      = 131072
    u64*      act2   = (u64*)(ws + 131072);         // 3*8*4096*8    = 786432
    uint16_t* table  = (uint16_t*)(ws + 917504);    // 12288*32*2    = 786432
    int*      counts = (int*)(ws + 1703936);        // 12288*4       = 49152
    short*    Ag     = (short*)(ws + 1753088);      // 512*12288*2   = 12582912
    short*    wt     = (short*)(ws + 14336000);     // 1024*12288*2  = 25165824

    hipMemsetAsync(d_out, 0, (size_t)BATCH * CLS * sizeof(float), stream);
    hipLaunchKernelGGL(k_prep, dim3(6656), dim3(256), 0, stream,
                       x, enc2, W0, W1, W2, table, counts, out_w, wt);
    hipLaunchKernelGGL(k_layer, dim3(HID * 8 / 4), dim3(256), 0, stream,
                       enc2, ENC, table, counts, act2);
    hipLaunchKernelGGL(k_layer, dim3(HID * 8 / 4), dim3(256), 0, stream,
                       act2, HID, table + (size_t)HID * 32, counts + HID, act2 + 8 * HID);
    hipLaunchKernelGGL(k_layer, dim3(HID * 8 / 4), dim3(256), 0, stream,
                       act2 + 8 * HID, HID, table + (size_t)2 * HID * 32, counts + 2 * HID,
                       act2 + 16 * HID);
    hipLaunchKernelGGL(k_expandA, dim3(3072), dim3(256), 0, stream, act2, Ag);
    hipLaunchKernelGGL(k_gemm, dim3(4 * 8 * NSPLIT), dim3(256), 0, stream, Ag, wt, out);
}

// Round 4
// 320.739 us; speedup vs baseline: 1.5159x; 1.0916x over previous
//
#include <hip/hip_runtime.h>
#include <stdint.h>

typedef unsigned long long u64;
typedef __attribute__((ext_vector_type(8))) short bf16x8;
typedef __attribute__((ext_vector_type(4))) float f32x4;

#define BATCH 512
#define FEAT 256
#define ENC 2048
#define HID 4096
#define CLS 1000
#define KTOT 12288      // 3 * 4096
#define NSPLIT 16
#define KSPLIT (KTOT / NSPLIT)   // 768
#define PARTLD 1024

// ws offsets
#define OFF_ENC2   0
#define OFF_ACT2   131072
#define OFF_TABLE  917504
#define OFF_COUNTS 1703936
#define OFF_AG     1753088
#define OFF_WT     14336000
#define OFF_PART   39501824
#define PART_BYTES (16ull * 512 * 1024 * 4)

// ---------- fp32 -> bf16 RNE ----------
static __device__ inline unsigned short f2bf(float f) {
    unsigned u = __float_as_uint(f);
    return (unsigned short)((u + 0x7FFFu + ((u >> 16) & 1u)) >> 16);
}

// ---------- async global->LDS, 16B/lane ----------
static __device__ inline void gld16(const void* g, void* s) {
    __builtin_amdgcn_global_load_lds((const __attribute__((address_space(1))) void*)g,
                                     (__attribute__((address_space(3))) void*)s, 16, 0, 0);
}

// ================= kernel 1: fused prep = encode | scan(sparsify) | twt =================
// blocks [0,512): encode   [512,5632): scan   [5632,8704): twt
__global__ void __launch_bounds__(256)
k_prep(const float* __restrict__ x, u64* __restrict__ enc2,
       const float* __restrict__ W0, const float* __restrict__ W1,
       const float* __restrict__ W2,
       uint16_t* __restrict__ table, int* __restrict__ counts,
       const float* __restrict__ out_w, short* __restrict__ wt) {
    __shared__ short tile[64 * 68];
    __shared__ int cnt4[4];
    int bid = blockIdx.x;
    int t = threadIdx.x;
    int lane = t & 63;
    int wv = t >> 6;

    if (bid < 512) {
        // ---- encode: bits packed OVER BATCH ----
        int wid = bid * 4 + wv;
        int f = wid >> 3, bg = wid & 7;
        float v = x[(size_t)(bg * 64 + lane) * FEAT + f];
        v = fminf(fmaxf(v, 0.0f), 1.0f);
        int lev = (int)rintf(v * 255.0f);                // RNE == jnp.round
        unsigned gray = (unsigned)(lev ^ (lev >> 1));
        u64 w = 0;
        #pragma unroll
        for (int bit = 0; bit < 8; ++bit) {
            u64 m = __ballot((gray >> bit) & 1u);
            if (lane == bit) w = m;
        }
        if (lane < 8) enc2[(size_t)bg * ENC + f * 8 + lane] = w;
        return;
    }
    if (bid < 5632) {
        // ---- scan: one wave scans exactly 2048 floats; LDS-atomic slot compaction ----
        if (t < 4) cnt4[t] = 0;
        __syncthreads();
        int ws = (bid - 512) * 4 + wv;       // 0..20479
        int row, base, cidx;
        if (ws < HID) { row = ws; base = 0; cidx = wv; }
        else {
            int w2 = ws - HID;               // 0..16383
            row = HID + (w2 >> 1);
            base = (w2 & 1) * 2048;
            cidx = wv >> 1;
        }
        const float* Wr;
        if (row < HID)          Wr = W0 + (size_t)row * ENC;
        else if (row < 2 * HID) Wr = W1 + (size_t)(row - HID) * HID + base;
        else                    Wr = W2 + (size_t)(row - 2 * HID) * HID + base;
        const uint4* p4 = (const uint4*)Wr;
        uint4 v[8];
        #pragma unroll
        for (int j = 0; j < 8; ++j) v[j] = p4[j * 64 + lane];
        uint16_t* te = table + (size_t)row * 32;
        #pragma unroll
        for (int j = 0; j < 8; ++j) {
            unsigned a0 = v[j].x, a1 = v[j].y, a2 = v[j].z, a3 = v[j].w;
            if (a0 | a1 | a2 | a3) {
                int col0 = base + j * 256 + lane * 4;
                if (a0) { int s = atomicAdd(&cnt4[cidx], 1);
                          te[s] = (uint16_t)((unsigned)col0       | ((a0 >> 16) & 0x8000u)); }
                if (a1) { int s = atomicAdd(&cnt4[cidx], 1);
                          te[s] = (uint16_t)((unsigned)(col0 + 1) | ((a1 >> 16) & 0x8000u)); }
                if (a2) { int s = atomicAdd(&cnt4[cidx], 1);
                          te[s] = (uint16_t)((unsigned)(col0 + 2) | ((a2 >> 16) & 0x8000u)); }
                if (a3) { int s = atomicAdd(&cnt4[cidx], 1);
                          te[s] = (uint16_t)((unsigned)(col0 + 3) | ((a3 >> 16) & 0x8000u)); }
            }
        }
        __syncthreads();
        if (lane == 0) counts[row] = cnt4[cidx];
        return;
    }
    {
        // ---- twt: transpose+convert out_w -> wt bf16 (swizzled) ----
        int b2 = bid - 5632;
        int kt = b2 % 192, ct = b2 / 192;
        int k0 = kt * 64, c0 = ct * 64;
        {
            int rrow = t >> 4, c4 = t & 15;
            int c = c0 + c4 * 4;
            #pragma unroll
            for (int rd = 0; rd < 4; ++rd) {
                int kl = rd * 16 + rrow;
                float4 vv;
                if (c < CLS) vv = *(const float4*)&out_w[(size_t)(k0 + kl) * CLS + c];
                else { vv.x = vv.y = vv.z = vv.w = 0.0f; }
                short* d = &tile[kl * 68 + c4 * 4];
                d[0] = (short)f2bf(vv.x); d[1] = (short)f2bf(vv.y);
                d[2] = (short)f2bf(vv.z); d[3] = (short)f2bf(vv.w);
            }
        }
        __syncthreads();
        {
            int chunk = t & 7, cl2 = t >> 3;
            #pragma unroll
            for (int rd = 0; rd < 2; ++rd) {
                int c_local = rd * 32 + cl2;
                int c = c0 + c_local;
                unsigned s8[8];
                #pragma unroll
                for (int j = 0; j < 8; ++j)
                    s8[j] = (unsigned)(unsigned short)tile[(chunk * 8 + j) * 68 + c_local];
                uint4 pk;
                pk.x = s8[0] | (s8[1] << 16);
                pk.y = s8[2] | (s8[3] << 16);
                pk.z = s8[4] | (s8[5] << 16);
                pk.w = s8[6] | (s8[7] << 16);
                *(uint4*)&wt[(size_t)c * KTOT + k0 + ((chunk ^ (c & 7)) * 8)] = pk;
            }
        }
    }
}

// ================= kernel 2: layer, lanes = batch, scalar-pipe synapse loads =========
__global__ void k_layer(const u64* __restrict__ prev2, int Kstride,
                        const uint16_t* __restrict__ table, const int* __restrict__ counts,
                        u64* __restrict__ actout) {
    int wid = __builtin_amdgcn_readfirstlane(blockIdx.x * 4 + (threadIdx.x >> 6));
    int lane = threadIdx.x & 63;
    int n = wid >> 3, bg = wid & 7;
    const u64* prow = prev2 + (size_t)bg * Kstride;
    const uint4* tq = (const uint4*)(table + (size_t)n * 32);
    int cnt = counts[n];
    int z = 0;
    #pragma unroll
    for (int q = 0; q < 4; ++q) {
        uint4 e4 = tq[q];
        unsigned es[4] = {e4.x, e4.y, e4.z, e4.w};
        #pragma unroll
        for (int h = 0; h < 4; ++h) {
            #pragma unroll
            for (int s2 = 0; s2 < 2; ++s2) {
                int e = q * 8 + h * 2 + s2;
                if (e < cnt) {
                    unsigned ent = (es[h] >> (s2 * 16)) & 0xFFFFu;
                    // force uniform -> scalar (s_load) path, frees VMEM pipe
                    int col = __builtin_amdgcn_readfirstlane((int)(ent & 0x7FFFu));
                    u64 w = prow[col];
                    int bit = (int)((w >> lane) & 1ull);
                    z += (ent & 0x8000u) ? -bit : bit;
                }
            }
        }
    }
    u64 res = __ballot(z >= 4);
    if (lane == 0) actout[(size_t)bg * HID + n] = res;
}

// ================= kernel 3: expand activation bits -> bf16 Ag (swizzled) =============
__global__ void k_expandA(const u64* __restrict__ act2, short* __restrict__ Ag) {
    int idx = blockIdx.x * 256 + threadIdx.x;     // 786432
    int b = idx / 1536;
    int rem = idx - b * 1536;
    int l = rem >> 9;
    int chunk = rem & 511;
    int bg = b >> 6, bl = b & 63;
    const u64* src = act2 + ((size_t)l * 8 + bg) * HID + chunk * 8;
    unsigned sh[8];
    #pragma unroll
    for (int j = 0; j < 8; ++j) sh[j] = ((src[j] >> bl) & 1ull) ? 0x3F80u : 0u;
    int g = chunk & 7, c64 = chunk >> 3;
    short* dst = Ag + (size_t)b * KTOT + l * HID + c64 * 64 + ((g ^ (b & 7)) * 8);
    uint4 pk;
    pk.x = sh[0] | (sh[1] << 16);
    pk.y = sh[2] | (sh[3] << 16);
    pk.z = sh[4] | (sh[5] << 16);
    pk.w = sh[6] | (sh[7] << 16);
    *(uint4*)dst = pk;
}

// ================= kernel 4: GEMM (MODE 0: partials, MODE 1: atomics) =================
template<int MODE>
__global__ void __launch_bounds__(256)
k_gemm(const short* __restrict__ Ag, const short* __restrict__ wt,
       float* __restrict__ out, float* __restrict__ part) {
    __shared__ __attribute__((aligned(16))) short As[128 * 64];
    __shared__ __attribute__((aligned(16))) short Bs[128 * 64];
    int bid = blockIdx.x;
    int mt = bid & 3, nt = (bid >> 2) & 7, ks = bid >> 5;
    int tid = threadIdx.x, lane = tid & 63;
    int wv = tid >> 6, waveM = wv & 1, waveN = wv >> 1;
    int quad = lane >> 4, cl = lane & 15;
    f32x4 acc[4][4] = {};
    const char* Ab = (const char*)(Ag + (size_t)mt * 128 * KTOT + ks * KSPLIT);
    const char* Bb = (const char*)(wt + (size_t)nt * 128 * KTOT + ks * KSPLIT);
    int r = tid >> 3, sub = tid & 7;
    for (int kk = 0; kk < KSPLIT; kk += 64) {
        #pragma unroll
        for (int rd = 0; rd < 4; ++rd) {
            size_t go = (size_t)(r + rd * 32) * (KTOT * 2) + kk * 2 + sub * 16;
            gld16(Ab + go, &As[(tid + rd * 256) * 8]);
            gld16(Bb + go, &Bs[(tid + rd * 256) * 8]);
        }
        __syncthreads();
        #pragma unroll
        for (int s = 0; s < 2; ++s) {
            int xr = ((s * 4 + quad) ^ (cl & 7)) * 8;
            bf16x8 af[4], bfr[4];
            #pragma unroll
            for (int mf = 0; mf < 4; ++mf)
                af[mf] = *(const bf16x8*)&As[(waveM * 64 + mf * 16 + cl) * 64 + xr];
            #pragma unroll
            for (int nf = 0; nf < 4; ++nf)
                bfr[nf] = *(const bf16x8*)&Bs[(waveN * 64 + nf * 16 + cl) * 64 + xr];
            #pragma unroll
            for (int mf = 0; mf < 4; ++mf)
                #pragma unroll
                for (int nf = 0; nf < 4; ++nf)
                    acc[mf][nf] = __builtin_amdgcn_mfma_f32_16x16x32_bf16(
                        af[mf], bfr[nf], acc[mf][nf], 0, 0, 0);
        }
        __syncthreads();
    }
    if (MODE == 0) {
        float* pbase = part + (size_t)ks * (BATCH * PARTLD);
        #pragma unroll
        for (int mf = 0; mf < 4; ++mf) {
            #pragma unroll
            for (int nf = 0; nf < 4; ++nf) {
                int cp = nt * 128 + waveN * 64 + nf * 16 + cl;
                #pragma unroll
                for (int rr = 0; rr < 4; ++rr) {
                    int mg = mt * 128 + waveM * 64 + mf * 16 + quad * 4 + rr;
                    pbase[(size_t)mg * PARTLD + cp] = acc[mf][nf][rr];
                }
            }
        }
    } else {
        #pragma unroll
        for (int mf = 0; mf < 4; ++mf) {
            #pragma unroll
            for (int nf = 0; nf < 4; ++nf) {
                int cp = nt * 128 + waveN * 64 + nf * 16 + cl;
                if (cp < CLS) {
                    #pragma unroll
                    for (int rr = 0; rr < 4; ++rr) {
                        int mg = mt * 128 + waveM * 64 + mf * 16 + quad * 4 + rr;
                        atomicAdd(&out[(size_t)mg * CLS + cp], acc[mf][nf][rr]);
                    }
                }
            }
        }
    }
}

// ================= kernel 5: reduce split-K partials into out ====================
__global__ void k_reduce(const float* __restrict__ part, float* __restrict__ out) {
    int idx = blockIdx.x * blockDim.x + threadIdx.x;
    if (idx >= BATCH * CLS) return;
    int b = idx / CLS, c = idx - b * CLS;
    float s = 0.0f;
    #pragma unroll
    for (int sp = 0; sp < NSPLIT; ++sp)
        s += part[((size_t)sp * BATCH + b) * PARTLD + c];
    out[idx] = s;
}

extern "C" void kernel_launch(void* const* d_in, const int* in_sizes, int n_in,
                              void* d_out, int out_size, void* d_ws, size_t ws_size,
                              hipStream_t stream) {
    const float* x     = (const float*)d_in[0];
    const float* W0    = (const float*)d_in[1];
    const float* W1    = (const float*)d_in[2];
    const float* W2    = (const float*)d_in[3];
    const float* out_w = (const float*)d_in[4];
    float* out = (float*)d_out;
    char* ws = (char*)d_ws;

    u64*      enc2   = (u64*)(ws + OFF_ENC2);
    u64*      act2   = (u64*)(ws + OFF_ACT2);
    uint16_t* table  = (uint16_t*)(ws + OFF_TABLE);
    int*      counts = (int*)(ws + OFF_COUNTS);
    short*    Ag     = (short*)(ws + OFF_AG);
    short*    wt     = (short*)(ws + OFF_WT);
    float*    part   = (float*)(ws + OFF_PART);

    bool use_part = ws_size >= (size_t)OFF_PART + PART_BYTES;

    hipLaunchKernelGGL(k_prep, dim3(8704), dim3(256), 0, stream,
                       x, enc2, W0, W1, W2, table, counts, out_w, wt);
    hipLaunchKernelGGL(k_layer, dim3(HID * 8 / 4), dim3(256), 0, stream,
                       enc2, ENC, table, counts, act2);
    hipLaunchKernelGGL(k_layer, dim3(HID * 8 / 4), dim3(256), 0, stream,
                       act2, HID, table + (size_t)HID * 32, counts + HID, act2 + 8 * HID);
    hipLaunchKernelGGL(k_layer, dim3(HID * 8 / 4), dim3(256), 0, stream,
                       act2 + 8 * HID, HID, table + (size_t)2 * HID * 32, counts + 2 * HID,
                       act2 + 16 * HID);
    hipLaunchKernelGGL(k_expandA, dim3(3072), dim3(256), 0, stream, act2, Ag);
    if (use_part) {
        hipLaunchKernelGGL((k_gemm<0>), dim3(4 * 8 * NSPLIT), dim3(256), 0, stream,
                           Ag, wt, out, part);
        hipLaunchKernelGGL(k_reduce, dim3((BATCH * CLS + 255) / 256), dim3(256), 0, stream,
                           part, out);
    } else {
        hipMemsetAsync(d_out, 0, (size_t)BATCH * CLS * sizeof(float), stream);
        hipLaunchKernelGGL((k_gemm<1>), dim3(4 * 8 * NSPLIT), dim3(256), 0, stream,
                           Ag, wt, out, part);
    }
}